// Round 2
// baseline (422.902 us; speedup 1.0000x reference)
//
#include <hip/hip_runtime.h>
#include <hip/hip_bf16.h>
#include <stdint.h>

// Problem constants
#define M_TOK   16384        // 8 * 2048 tokens
#define EMBED   1024
#define FFN     4096
#define NQ      10

typedef __attribute__((ext_vector_type(8))) short  bf16x8;
typedef __attribute__((ext_vector_type(4))) float  f32x4;
typedef __attribute__((ext_vector_type(8))) unsigned short u16x8;

static __device__ __forceinline__ unsigned short f2bf(float f) {
    union { float f; unsigned u; } v; v.f = f;
    unsigned r = v.u + 0x7FFF + ((v.u >> 16) & 1);   // round-to-nearest-even
    return (unsigned short)(r >> 16);
}

// ---------------------------------------------------------------------------
// Kernel 1: h[t][f] = relu( sum_i cos(x[t][i]) * cos(ry[i]) * w1[f][i] ) -> bf16
// grid (128 token-tiles, 2 f-tiles), 256 threads.
// Each thread: 8 consecutive f, 128 tokens; u16x8 stores (16B/lane, coalesced).
// ---------------------------------------------------------------------------
__global__ __launch_bounds__(256) void compute_h(
    const float* __restrict__ x, const float* __restrict__ ry,
    const float* __restrict__ w1, unsigned short* __restrict__ h)
{
    __shared__ float cq[128 * NQ];   // cos(x) for 128 tokens (5 KB)
    __shared__ float cry[NQ];

    const int tid = threadIdx.x;
    const int t0  = blockIdx.x * 128;
    const int fb  = blockIdx.y * 2048 + tid * 8;   // this thread's 8 f's

    if (tid < NQ) cry[tid] = cosf(ry[tid]);
    for (int idx = tid; idx < 128 * NQ; idx += 256) {
        int t = idx / NQ;
        int i = idx - t * NQ;
        cq[idx] = cosf(x[(size_t)(t0 + t) * EMBED + i]);
    }
    __syncthreads();

    // premultiply w1 rows by cos(phi): 80 floats in registers
    float wf[8][NQ];
#pragma unroll
    for (int fi = 0; fi < 8; ++fi)
#pragma unroll
        for (int i = 0; i < NQ; ++i)
            wf[fi][i] = w1[(fb + fi) * NQ + i] * cry[i];

    for (int t = 0; t < 128; ++t) {
        u16x8 v;
#pragma unroll
        for (int fi = 0; fi < 8; ++fi) {
            float s = 0.f;
#pragma unroll
            for (int i = 0; i < NQ; ++i) s += cq[t * NQ + i] * wf[fi][i];
            v[fi] = f2bf(fmaxf(s, 0.f));
        }
        *(u16x8*)(h + (size_t)(t0 + t) * FFN + fb) = v;
    }
}

// ---------------------------------------------------------------------------
// Kernel 2: w2 fp32 -> bf16.  4,194,304 elems, 8 per thread.
// ---------------------------------------------------------------------------
__global__ __launch_bounds__(256) void conv_w2(
    const float* __restrict__ w2, unsigned short* __restrict__ o)
{
    const int idx = (blockIdx.x * 256 + threadIdx.x) * 8;
    float4 a = *(const float4*)(w2 + idx);
    float4 b = *(const float4*)(w2 + idx + 4);
    u16x8 v;
    v[0] = f2bf(a.x); v[1] = f2bf(a.y); v[2] = f2bf(a.z); v[3] = f2bf(a.w);
    v[4] = f2bf(b.x); v[5] = f2bf(b.y); v[6] = f2bf(b.z); v[7] = f2bf(b.w);
    *(u16x8*)(o + idx) = v;
}

// ---------------------------------------------------------------------------
// Kernel 3: C[M][N] = A[M][K] * B[N][K]^T   (bf16 in, fp32 out)
// 128x128 block tile, BK=32, 4 waves (2x2), wave = 64x64 via 4x4 MFMA tiles.
//
// LDS layout is CHUNK-MAJOR per 16-row tile: tile = 1 KB, unit (c,r) at
// offset (c*16+r)*16 bytes, c = k-chunk (8 bf16 = 16B), r = row in tile.
// MFMA fragment for lane = (row=lane&15, chunk=lane>>4), so the fragment
// read address is tile_base + lane*16 -> linear, ZERO bank conflicts.
// global_load_lds slots (base + lane*16) are fed the matching global data
// (row = lane&15, chunk = lane>>4) -- a pure permutation of R0's staging.
//
// Grid: 1D 1024 blocks, swizzled so the 8 n-blocks sharing one A m-tile get
// the SAME id%8 (-> same XCD, assuming round-robin) and adjacent dispatch:
// A-tile fetched once per XCD L2, 8x reuse.
// ---------------------------------------------------------------------------
#define GK 4096
#define GN 1024

#define GL2LDS(g, l) \
    __builtin_amdgcn_global_load_lds( \
        (const __attribute__((address_space(1))) void*)(g), \
        (__attribute__((address_space(3))) void*)(l), 16, 0, 0)

__global__ __launch_bounds__(256) void gemm_bt(
    const unsigned short* __restrict__ A,
    const unsigned short* __restrict__ B,
    float* __restrict__ C)
{
    __shared__ unsigned short At[128 * 32];   // 8 KB = 8 tiles x 1 KB
    __shared__ unsigned short Bt[128 * 32];   // 8 KB

    const int tid  = threadIdx.x;
    const int wv   = tid >> 6;
    const int lane = tid & 63;

    // XCD-aware decode: within a 64-block group, id%8 = m residue.
    const int bid   = blockIdx.x;
    const int group = bid >> 6;            // 0..15
    const int g     = bid & 63;
    const int m_blk = group * 8 + (g & 7); // 0..127
    const int n_blk = g >> 3;              // 0..7
    const int m0 = m_blk * 128;
    const int n0 = n_blk * 128;

    const int wrt = (wv & 1) * 4;      // wave row-tile base (16-row tiles)
    const int wct = (wv >> 1) * 4;     // wave col-tile base

    f32x4 acc[4][4] = {};

    // staging: lane -> (row = lane&15, chunk = lane>>4) of a 16-row tile
    const int srow  = lane & 15;
    const int scolb = (lane >> 4) * 16;    // byte offset within row's 64B

    for (int k0 = 0; k0 < GK; k0 += 32) {
#pragma unroll
        for (int j = 0; j < 2; ++j) {
            const int ti = wv * 2 + j;     // tile 0..7
            const char* ag = (const char*)A +
                (((size_t)(m0 + ti * 16 + srow) * GK + k0) * 2 + scolb);
            GL2LDS(ag, (char*)At + ti * 1024);
            const char* bg = (const char*)B +
                (((size_t)(n0 + ti * 16 + srow) * GK + k0) * 2 + scolb);
            GL2LDS(bg, (char*)Bt + ti * 1024);
        }
        __syncthreads();

        bf16x8 af[4], bf[4];
#pragma unroll
        for (int i = 0; i < 4; ++i) {
            af[i] = *(const bf16x8*)((const char*)At + (wrt + i) * 1024 + lane * 16);
            bf[i] = *(const bf16x8*)((const char*)Bt + (wct + i) * 1024 + lane * 16);
        }
#pragma unroll
        for (int i = 0; i < 4; ++i)
#pragma unroll
            for (int j = 0; j < 4; ++j)
                acc[i][j] = __builtin_amdgcn_mfma_f32_16x16x32_bf16(
                    af[i], bf[j], acc[i][j], 0, 0, 0);
        __syncthreads();
    }

    // epilogue: C/D layout col = lane&15, row = (lane>>4)*4 + reg
    const int cn    = lane & 15;
    const int rbase = (lane >> 4) * 4;
#pragma unroll
    for (int i = 0; i < 4; ++i)
#pragma unroll
        for (int j = 0; j < 4; ++j)
#pragma unroll
            for (int r = 0; r < 4; ++r) {
                const int m = m0 + wrt * 16 + i * 16 + rbase + r;
                const int n = n0 + wct * 16 + j * 16 + cn;
                C[(size_t)m * GN + n] = acc[i][j][r];
            }
}

// ---------------------------------------------------------------------------
extern "C" void kernel_launch(void* const* d_in, const int* in_sizes, int n_in,
                              void* d_out, int out_size, void* d_ws, size_t ws_size,
                              hipStream_t stream) {
    const float* x  = (const float*)d_in[0];
    const float* ry = (const float*)d_in[1];
    const float* w1 = (const float*)d_in[2];
    const float* w2 = (const float*)d_in[3];
    float* out = (float*)d_out;

    unsigned short* h   = (unsigned short*)d_ws;                       // 128 MiB
    unsigned short* w2b = (unsigned short*)((char*)d_ws +
                           (size_t)M_TOK * FFN * sizeof(unsigned short));

    compute_h<<<dim3(128, 2), 256, 0, stream>>>(x, ry, w1, h);
    conv_w2<<<dim3((EMBED * FFN) / (256 * 8)), 256, 0, stream>>>(w2, w2b);
    gemm_bt<<<dim3(1024), 256, 0, stream>>>(h, w2b, out);
}

// Round 4
// 332.849 us; speedup vs baseline: 1.2706x; 1.2706x over previous
//
#include <hip/hip_runtime.h>
#include <hip/hip_bf16.h>
#include <stdint.h>

// Problem constants
#define M_TOK   16384        // 8 * 2048 tokens
#define EMBED   1024
#define FFN     4096
#define NQ      10

typedef __attribute__((ext_vector_type(8))) short  bf16x8;
typedef __attribute__((ext_vector_type(4))) float  f32x4;
typedef __attribute__((ext_vector_type(8))) unsigned short u16x8;
typedef __attribute__((ext_vector_type(4))) unsigned short u16x4;

static __device__ __forceinline__ unsigned short f2bf(float f) {
    union { float f; unsigned u; } v; v.f = f;
    unsigned r = v.u + 0x7FFF + ((v.u >> 16) & 1);   // round-to-nearest-even
    return (unsigned short)(r >> 16);
}

// ---------------------------------------------------------------------------
// Kernel 1: h[t][f] = relu( sum_i cos(x[t][i]) * cos(ry[i]) * w1[f][i] ) -> bf16
// grid (128 token-tiles, 4 f-tiles), 256 threads, 4 f per thread (40-reg w1
// table -- no spill), u16x4 stores (8B/lane, coalesced).
// ---------------------------------------------------------------------------
__global__ __launch_bounds__(256) void compute_h(
    const float* __restrict__ x, const float* __restrict__ ry,
    const float* __restrict__ w1, unsigned short* __restrict__ h)
{
    __shared__ float cq[128 * NQ];   // cos(x) for 128 tokens (5 KB)
    __shared__ float cry[NQ];

    const int tid = threadIdx.x;
    const int t0  = blockIdx.x * 128;
    const int fb  = blockIdx.y * 1024 + tid * 4;   // this thread's 4 f's

    if (tid < NQ) cry[tid] = cosf(ry[tid]);
    for (int idx = tid; idx < 128 * NQ; idx += 256) {
        int t = idx / NQ;
        int i = idx - t * NQ;
        cq[idx] = cosf(x[(size_t)(t0 + t) * EMBED + i]);
    }
    __syncthreads();

    float wf[4][NQ];
#pragma unroll
    for (int fi = 0; fi < 4; ++fi)
#pragma unroll
        for (int i = 0; i < NQ; ++i)
            wf[fi][i] = w1[(fb + fi) * NQ + i] * cry[i];

    for (int t = 0; t < 128; ++t) {
        u16x4 v;
#pragma unroll
        for (int fi = 0; fi < 4; ++fi) {
            float s = 0.f;
#pragma unroll
            for (int i = 0; i < NQ; ++i) s += cq[t * NQ + i] * wf[fi][i];
            v[fi] = f2bf(fmaxf(s, 0.f));
        }
        *(u16x4*)(h + (size_t)(t0 + t) * FFN + fb) = v;
    }
}

// ---------------------------------------------------------------------------
// Kernel 2: w2 fp32 -> bf16.  4,194,304 elems, 8 per thread.
// ---------------------------------------------------------------------------
__global__ __launch_bounds__(256) void conv_w2(
    const float* __restrict__ w2, unsigned short* __restrict__ o)
{
    const int idx = (blockIdx.x * 256 + threadIdx.x) * 8;
    float4 a = *(const float4*)(w2 + idx);
    float4 b = *(const float4*)(w2 + idx + 4);
    u16x8 v;
    v[0] = f2bf(a.x); v[1] = f2bf(a.y); v[2] = f2bf(a.z); v[3] = f2bf(a.w);
    v[4] = f2bf(b.x); v[5] = f2bf(b.y); v[6] = f2bf(b.z); v[7] = f2bf(b.w);
    *(u16x8*)(o + idx) = v;
}

// ---------------------------------------------------------------------------
// Kernel 3: C[M][N] = A[M][K] * B[N][K]^T   (bf16 in, fp32 out)
// 128x128 tile, BK=32, 4 waves (2x2), wave = 64x64 via 4x4 MFMA 16x16x32.
//
// Staging (global side, R0-coalesced): lane -> row r = lane>>2 of a 16-row
// tile; 4 lanes of a row cover its full 64B line, but each lane fetches
// chunk c = (lane&3) ^ f(r), f(r) = (r>>1)&3.  Still one 64B txn per row.
// LDS image (lane*16 linear): LDS[r][j] = global chunk j ^ f(r).
//
// Fragment read (lane: rr=lane&15, cc=lane>>4): addr = rr*64 + (cc^f(rr))*16.
// Any 8 consecutive lanes hit 8 distinct 16B bank-groups -> conflict-free,
// AND the XOR resolves to the correct chunk: (cc^f)^f = cc.
//
// Grid: 1D 1024 blocks; within a 64-block group id%8 = m residue so the 8
// n-blocks sharing an A m-tile land on the same XCD, adjacent in time.
// ---------------------------------------------------------------------------
#define GK 4096
#define GN 1024

#define GL2LDS(g, l) \
    __builtin_amdgcn_global_load_lds( \
        (const __attribute__((address_space(1))) void*)(g), \
        (__attribute__((address_space(3))) void*)(l), 16, 0, 0)

__global__ __launch_bounds__(256) void gemm_bt(
    const unsigned short* __restrict__ A,
    const unsigned short* __restrict__ B,
    float* __restrict__ C)
{
    __shared__ unsigned short At[128 * 32];   // 8 KB = 8 tiles x [16 rows][64B]
    __shared__ unsigned short Bt[128 * 32];   // 8 KB

    const int tid  = threadIdx.x;
    const int wv   = tid >> 6;
    const int lane = tid & 63;

    // XCD-aware decode
    const int bid   = blockIdx.x;
    const int group = bid >> 6;            // 0..15
    const int g     = bid & 63;
    const int m_blk = group * 8 + (g & 7); // 0..127
    const int n_blk = g >> 3;              // 0..7
    const int m0 = m_blk * 128;
    const int n0 = n_blk * 128;

    const int wrt = (wv & 1) * 4;      // wave row-tile base (16-row tiles)
    const int wct = (wv >> 1) * 4;     // wave col-tile base

    f32x4 acc[4][4] = {};

    // staging: lane -> row = lane>>2, fetched chunk = (lane&3) ^ ((row>>1)&3)
    const int srow  = lane >> 2;                                // 0..15
    const int scolb = ((lane & 3) ^ ((srow >> 1) & 3)) * 16;    // byte in row

    // fragment read offsets (constant per lane)
    const int rr = lane & 15;
    const int cc = lane >> 4;
    const int frag_off = rr * 64 + ((cc ^ ((rr >> 1) & 3)) * 16);

    for (int k0 = 0; k0 < GK; k0 += 32) {
#pragma unroll
        for (int j = 0; j < 2; ++j) {
            const int ti = wv * 2 + j;     // tile 0..7
            const char* ag = (const char*)A +
                (((size_t)(m0 + ti * 16 + srow) * GK + k0) * 2 + scolb);
            GL2LDS(ag, (char*)At + ti * 1024);
            const char* bg = (const char*)B +
                (((size_t)(n0 + ti * 16 + srow) * GK + k0) * 2 + scolb);
            GL2LDS(bg, (char*)Bt + ti * 1024);
        }
        __syncthreads();

        bf16x8 af[4], bf[4];
#pragma unroll
        for (int i = 0; i < 4; ++i) {
            af[i] = *(const bf16x8*)((const char*)At + (wrt + i) * 1024 + frag_off);
            bf[i] = *(const bf16x8*)((const char*)Bt + (wct + i) * 1024 + frag_off);
        }
#pragma unroll
        for (int i = 0; i < 4; ++i)
#pragma unroll
            for (int j = 0; j < 4; ++j)
                acc[i][j] = __builtin_amdgcn_mfma_f32_16x16x32_bf16(
                    af[i], bf[j], acc[i][j], 0, 0, 0);
        __syncthreads();
    }

    // epilogue: C/D layout col = lane&15, row = (lane>>4)*4 + reg
    const int cn    = lane & 15;
    const int rbase = (lane >> 4) * 4;
#pragma unroll
    for (int i = 0; i < 4; ++i)
#pragma unroll
        for (int j = 0; j < 4; ++j)
#pragma unroll
            for (int r = 0; r < 4; ++r) {
                const int m = m0 + wrt * 16 + i * 16 + rbase + r;
                const int n = n0 + wct * 16 + j * 16 + cn;
                C[(size_t)m * GN + n] = acc[i][j][r];
            }
}

// ---------------------------------------------------------------------------
extern "C" void kernel_launch(void* const* d_in, const int* in_sizes, int n_in,
                              void* d_out, int out_size, void* d_ws, size_t ws_size,
                              hipStream_t stream) {
    const float* x  = (const float*)d_in[0];
    const float* ry = (const float*)d_in[1];
    const float* w1 = (const float*)d_in[2];
    const float* w2 = (const float*)d_in[3];
    float* out = (float*)d_out;

    unsigned short* h   = (unsigned short*)d_ws;                       // 128 MiB
    unsigned short* w2b = (unsigned short*)((char*)d_ws +
                           (size_t)M_TOK * FFN * sizeof(unsigned short));

    compute_h<<<dim3(128, 4), 256, 0, stream>>>(x, ry, w1, h);
    conv_w2<<<dim3((EMBED * FFN) / (256 * 8)), 256, 0, stream>>>(w2, w2b);
    gemm_bt<<<dim3(1024), 256, 0, stream>>>(h, w2b, out);
}

// Round 5
// 293.012 us; speedup vs baseline: 1.4433x; 1.1360x over previous
//
#include <hip/hip_runtime.h>
#include <hip/hip_bf16.h>
#include <stdint.h>

// Problem constants
#define M_TOK   16384        // 8 * 2048 tokens
#define EMBED   1024
#define FFN     4096
#define NQ      10

typedef __attribute__((ext_vector_type(8))) short  bf16x8;
typedef __attribute__((ext_vector_type(4))) float  f32x4;
typedef __attribute__((ext_vector_type(8))) unsigned short u16x8;

static __device__ __forceinline__ unsigned short f2bf(float f) {
    union { float f; unsigned u; } v; v.f = f;
    unsigned r = v.u + 0x7FFF + ((v.u >> 16) & 1);   // round-to-nearest-even
    return (unsigned short)(r >> 16);
}

// ---------------------------------------------------------------------------
// Kernel 1: h[t][f] = relu( sum_i cos(x[t][i]) * cos(ry[i]) * w1[f][i] ) -> bf16
// grid (512 token-tiles of 32, 2 f-tiles), 256 threads, 8 f per thread.
// cq padded to stride 16 -> vectorized LDS reads (b128+b128+b64, 3 issues
// instead of 10 scalar). 1024 blocks = 4/CU for latency hiding.
// ---------------------------------------------------------------------------
__global__ __launch_bounds__(256) void compute_h(
    const float* __restrict__ x, const float* __restrict__ ry,
    const float* __restrict__ w1, unsigned short* __restrict__ h)
{
    __shared__ float cq[32 * 16];    // 2 KB, stride 16 for alignment
    __shared__ float cry[NQ];

    const int tid = threadIdx.x;
    const int t0  = blockIdx.x * 32;
    const int fb  = blockIdx.y * 2048 + tid * 8;   // this thread's 8 f's

    if (tid < NQ) cry[tid] = cosf(ry[tid]);
    for (int idx = tid; idx < 32 * NQ; idx += 256) {
        int t = idx / NQ;
        int i = idx - t * NQ;
        cq[t * 16 + i] = cosf(x[(size_t)(t0 + t) * EMBED + i]);
    }
    __syncthreads();

    // premultiply w1 rows by cos(phi): 80 floats in registers
    float wf[8][NQ];
#pragma unroll
    for (int fi = 0; fi < 8; ++fi)
#pragma unroll
        for (int i = 0; i < NQ; ++i)
            wf[fi][i] = w1[(fb + fi) * NQ + i] * cry[i];

    for (int t = 0; t < 32; ++t) {
        const float4 c0 = *(const float4*)&cq[t * 16 + 0];
        const float4 c1 = *(const float4*)&cq[t * 16 + 4];
        const float2 c2 = *(const float2*)&cq[t * 16 + 8];
        u16x8 v;
#pragma unroll
        for (int fi = 0; fi < 8; ++fi) {
            float s = c0.x * wf[fi][0] + c0.y * wf[fi][1] + c0.z * wf[fi][2]
                    + c0.w * wf[fi][3] + c1.x * wf[fi][4] + c1.y * wf[fi][5]
                    + c1.z * wf[fi][6] + c1.w * wf[fi][7] + c2.x * wf[fi][8]
                    + c2.y * wf[fi][9];
            v[fi] = f2bf(fmaxf(s, 0.f));
        }
        *(u16x8*)(h + (size_t)(t0 + t) * FFN + fb) = v;
    }
}

// ---------------------------------------------------------------------------
// Kernel 2: w2 fp32 -> bf16.  4,194,304 elems, 8 per thread.
// ---------------------------------------------------------------------------
__global__ __launch_bounds__(256) void conv_w2(
    const float* __restrict__ w2, unsigned short* __restrict__ o)
{
    const int idx = (blockIdx.x * 256 + threadIdx.x) * 8;
    float4 a = *(const float4*)(w2 + idx);
    float4 b = *(const float4*)(w2 + idx + 4);
    u16x8 v;
    v[0] = f2bf(a.x); v[1] = f2bf(a.y); v[2] = f2bf(a.z); v[3] = f2bf(a.w);
    v[4] = f2bf(b.x); v[5] = f2bf(b.y); v[6] = f2bf(b.z); v[7] = f2bf(b.w);
    *(u16x8*)(o + idx) = v;
}

// ---------------------------------------------------------------------------
// Kernel 3: C[M][N] = A[M][K] * B[N][K]^T   (bf16 in, fp32 out)
// 128x128 tile, BK=64 (64 K-iters, half the barrier drains of BK=32),
// 4 waves (2x2), wave = 64x64 via 4x4 MFMA 16x16x32, 2 k-steps per iter.
//
// LDS row = 128 B = 8 chunks of 16 B.  Staging: lane -> (row = lane>>3,
// chunk = (lane&7) ^ (lane>>3)): 8 lanes cover one full 128 B row line
// (coalesced), image LDS[r][c] = global[r][c ^ (r&7)].
// Fragment (rr=lane&15, cc=lane>>4, k-step s): slot (s*4+cc) ^ (rr&7)
// -> round-trips to global chunk s*4+cc; 16-lane phase spreads 8 bank
// groups at 2-way aliasing (free, m136).
//
// Grid: 1D 1024 blocks; id%8 = m residue within a 64-block group so the 8
// n-blocks sharing an A m-tile land on the same XCD.
// ---------------------------------------------------------------------------
#define GK 4096
#define GN 1024
#define BK 64

#define GL2LDS(g, l) \
    __builtin_amdgcn_global_load_lds( \
        (const __attribute__((address_space(1))) void*)(g), \
        (__attribute__((address_space(3))) void*)(l), 16, 0, 0)

__global__ __launch_bounds__(256) void gemm_bt(
    const unsigned short* __restrict__ A,
    const unsigned short* __restrict__ B,
    float* __restrict__ C)
{
    __shared__ unsigned short At[128 * BK];   // 16 KB: [128 rows][128 B]
    __shared__ unsigned short Bt[128 * BK];   // 16 KB

    const int tid  = threadIdx.x;
    const int wv   = tid >> 6;
    const int lane = tid & 63;

    // XCD-aware decode
    const int bid   = blockIdx.x;
    const int group = bid >> 6;            // 0..15
    const int g     = bid & 63;
    const int m_blk = group * 8 + (g & 7); // 0..127
    const int n_blk = g >> 3;              // 0..7
    const int m0 = m_blk * 128;
    const int n0 = n_blk * 128;

    const int wr = (wv & 1) * 64;      // wave row offset (rows)
    const int wc = (wv >> 1) * 64;     // wave col offset

    f32x4 acc[4][4] = {};

    // staging: lane -> row_in_group = lane>>3, chunk = (lane&7)^(lane>>3)
    const int srow  = lane >> 3;                       // 0..7
    const int scolb = ((lane & 7) ^ srow) * 16;        // byte offset in row

    // fragment read offsets (constant per lane), one per k-step
    const int rr = lane & 15;
    const int cc = lane >> 4;
    const int f0off = rr * 128 + (((0 * 4 + cc) ^ (rr & 7)) * 16);
    const int f1off = rr * 128 + (((1 * 4 + cc) ^ (rr & 7)) * 16);

    for (int k0 = 0; k0 < GK; k0 += BK) {
#pragma unroll
        for (int j = 0; j < 4; ++j) {
            const int rbase = wv * 32 + j * 8;     // row group base (mult of 8)
            const char* ag = (const char*)A +
                (((size_t)(m0 + rbase + srow) * GK + k0) * 2 + scolb);
            GL2LDS(ag, (char*)At + rbase * 128);
            const char* bg = (const char*)B +
                (((size_t)(n0 + rbase + srow) * GK + k0) * 2 + scolb);
            GL2LDS(bg, (char*)Bt + rbase * 128);
        }
        __syncthreads();

#pragma unroll
        for (int s = 0; s < 2; ++s) {
            const int foff = s ? f1off : f0off;
            bf16x8 af[4], bf[4];
#pragma unroll
            for (int i = 0; i < 4; ++i) {
                af[i] = *(const bf16x8*)((const char*)At + (wr + i * 16) * 128 + foff);
                bf[i] = *(const bf16x8*)((const char*)Bt + (wc + i * 16) * 128 + foff);
            }
#pragma unroll
            for (int i = 0; i < 4; ++i)
#pragma unroll
                for (int j = 0; j < 4; ++j)
                    acc[i][j] = __builtin_amdgcn_mfma_f32_16x16x32_bf16(
                        af[i], bf[j], acc[i][j], 0, 0, 0);
        }
        __syncthreads();
    }

    // epilogue: C/D layout col = lane&15, row = (lane>>4)*4 + reg
    const int cn    = lane & 15;
    const int rbase = (lane >> 4) * 4;
#pragma unroll
    for (int i = 0; i < 4; ++i)
#pragma unroll
        for (int j = 0; j < 4; ++j)
#pragma unroll
            for (int r = 0; r < 4; ++r) {
                const int m = m0 + wr + i * 16 + rbase + r;
                const int n = n0 + wc + j * 16 + cn;
                C[(size_t)m * GN + n] = acc[i][j][r];
            }
}

// ---------------------------------------------------------------------------
extern "C" void kernel_launch(void* const* d_in, const int* in_sizes, int n_in,
                              void* d_out, int out_size, void* d_ws, size_t ws_size,
                              hipStream_t stream) {
    const float* x  = (const float*)d_in[0];
    const float* ry = (const float*)d_in[1];
    const float* w1 = (const float*)d_in[2];
    const float* w2 = (const float*)d_in[3];
    float* out = (float*)d_out;

    unsigned short* h   = (unsigned short*)d_ws;                       // 128 MiB
    unsigned short* w2b = (unsigned short*)((char*)d_ws +
                           (size_t)M_TOK * FFN * sizeof(unsigned short));

    compute_h<<<dim3(512, 2), 256, 0, stream>>>(x, ry, w1, h);
    conv_w2<<<dim3((EMBED * FFN) / (256 * 8)), 256, 0, stream>>>(w2, w2b);
    gemm_bt<<<dim3(1024), 256, 0, stream>>>(h, w2b, out);
}